// Round 12
// baseline (600.162 us; speedup 1.0000x reference)
//
#include <hip/hip_runtime.h>
#include <math.h>

#define T_ 512
#define B_ 64
#define V_ 50000
#define E_ 300
#define H_ 256
#define K_ 20
#define G4 1024  /* 4*H */
#define LOG2E 1.44269504f
#define LN2 0.69314718f

typedef float f4 __attribute__((ext_vector_type(4)));
typedef int v4i __attribute__((ext_vector_type(4)));
typedef int v8i __attribute__((ext_vector_type(8)));
typedef short bf16x8 __attribute__((ext_vector_type(8)));
typedef _Float16 h2_t __attribute__((ext_vector_type(2)));
union U32H2 { unsigned u; h2_t h; };
__device__ __forceinline__ h2_t u2h(unsigned u) { U32H2 x; x.u = u; return x.h; }
__device__ __forceinline__ unsigned h2u(h2_t h) { U32H2 x; x.h = h; return x.u; }

__device__ __forceinline__ float rcpf(float x) { return __builtin_amdgcn_rcpf(x); }
__device__ __forceinline__ float exp2f_(float x) { return __builtin_amdgcn_exp2f(x); }

__device__ __forceinline__ unsigned short f32_bf16(float x) {
  union { float f; unsigned u; } v; v.f = x;
  v.u += 0x7FFFu + ((v.u >> 16) & 1u);   // RTNE
  return (unsigned short)(v.u >> 16);
}

// e2m1 (fp4) quantizer: values {0,.5,1,1.5,2,3,4,6}, RTNE thresholds at midpoints.
__device__ __forceinline__ unsigned f32_e2m1(float x) {
  float a = fabsf(x);
  unsigned m = (a >= 0.25f) + (a >= 0.75f) + (a >= 1.25f) + (a >= 1.75f)
             + (a >= 2.5f)  + (a >= 3.5f)  + (a >= 5.f);
  return (x < 0.f ? 8u : 0u) | m;
}

// undef-extend a v4i to the v8i operand slot (fp4 fmt reads only v[0:3])
__device__ __forceinline__ v8i ext8(v4i x) {
  return __builtin_shufflevector(x, x, 0, 1, 2, 3, -1, -1, -1, -1);
}

// LDS-only barrier (R2: neutral vs __syncthreads; keeps vmcnt in flight).
__device__ __forceinline__ void block_sync_lds() {
  asm volatile("s_waitcnt lgkmcnt(0)" ::: "memory");
  __builtin_amdgcn_s_barrier();
}

#define WSCALE4 64.f     /* fp4 e2m1 weight scale: w*64 in [-4,4] */
#define HSCALE4 4.f      /* fp4 e2m1 h scale: h*4 in [-4,4] */
#define DESCALE4 (LOG2E / (WSCALE4 * HSCALE4))
#define SC1 0x7F7F7F7F   /* e8m0 exponent 127 = scale 1.0 (all 4 MX blocks) */

// ---- prep: gather X=bf16(emb[inp]) (K padded to 320), pack w_ih A-frags, quantize w_hh fp4,
//      combine biases, zero out ------------------------------------------------------------
__global__ void prep_kernel(const int* __restrict__ inp,
                            const float* __restrict__ emb,
                            const float* __restrict__ w_ih, const float* __restrict__ w_hh,
                            const float* __restrict__ b_ih, const float* __restrict__ b_hh,
                            unsigned short* __restrict__ Xh, unsigned short* __restrict__ wA,
                            unsigned char* __restrict__ W4,
                            float* __restrict__ b_comb, float* __restrict__ out) {
  int tid = blockIdx.x * blockDim.x + threadIdx.x;
  int nth = gridDim.x * blockDim.x;
  for (int i = tid; i < 32768 * 80; i += nth) {
    int row = i / 80, c4 = i % 80, k = c4 * 4;
    ushort4 st;
    if (c4 < 75) {
      int tok = inp[row];
      float4 v = *(const float4*)(emb + (long)tok * E_ + k);
      st.x = f32_bf16(v.x); st.y = f32_bf16(v.y); st.z = f32_bf16(v.z); st.w = f32_bf16(v.w);
    } else {
      st.x = st.y = st.z = st.w = 0;
    }
    *(ushort4*)(Xh + (long)row * 320 + k) = st;
  }
  for (int i = tid; i < 10 * 4 * 1024 * 8; i += nth) {
    int j = i & 7, n = (i >> 3) & 1023, q = (i >> 13) & 3, c = i >> 15;
    int k = c * 32 + q * 8 + j;
    wA[i] = (k < E_) ? f32_bf16(w_ih[n * E_ + k]) : 0;
  }
  // W4[row][kb] = e2m1(w[row][2kb]*64) | e2m1(w[row][2kb+1]*64)<<4  (nibble k-pairs)
  for (int i = tid; i < G4 * (H_ / 2); i += nth) {
    int row = i >> 7, kb = i & 127;
    unsigned lo = f32_e2m1(w_hh[row * H_ + 2 * kb]     * WSCALE4);
    unsigned hi = f32_e2m1(w_hh[row * H_ + 2 * kb + 1] * WSCALE4);
    W4[i] = (unsigned char)(lo | (hi << 4));
  }
  for (int i = tid; i < G4; i += nth) b_comb[i] = b_ih[i] + b_hh[i];
  if (tid == 0) out[0] = 0.f;
}

// ---- kernel A: g_in (f16) = (X @ w_ih^T + b) * log2(e), via bf16 MFMA ---------------------
__global__ __launch_bounds__(256) void kernelA(const unsigned short* __restrict__ Xh,
                                               const unsigned short* __restrict__ wA,
                                               const float* __restrict__ b_comb,
                                               _Float16* __restrict__ g_in) {
  __shared__ __align__(16) unsigned short xs[32 * 328];
  int bm = blockIdx.x >> 2, bn = blockIdx.x & 3;
  int tid = threadIdx.x;
  for (int i = tid; i < 32 * 40; i += 256) {
    int r = i / 40, c = i % 40;
    *(uint4*)&xs[r * 328 + c * 8] = *(const uint4*)(Xh + (long)(bm * 32 + r) * 320 + c * 8);
  }
  __syncthreads();
  int lane = tid & 63, w = tid >> 6, col = lane & 15, quad = lane >> 4;
  int nbase = bn * 256 + w * 64;
  f4 acc[2][4];
#pragma unroll
  for (int mt = 0; mt < 2; mt++)
#pragma unroll
    for (int nt = 0; nt < 4; nt++) acc[mt][nt] = (f4){0.f, 0.f, 0.f, 0.f};
#pragma unroll 2
  for (int c = 0; c < 10; c++) {
    bf16x8 a[4], b[2];
#pragma unroll
    for (int nt = 0; nt < 4; nt++)
      a[nt] = *(const bf16x8*)(wA + (((long)c * 4 + quad) * 1024 + nbase + nt * 16 + col) * 8);
#pragma unroll
    for (int mt = 0; mt < 2; mt++)
      b[mt] = *(const bf16x8*)&xs[(mt * 16 + col) * 328 + c * 32 + quad * 8];
#pragma unroll
    for (int mt = 0; mt < 2; mt++)
#pragma unroll
      for (int nt = 0; nt < 4; nt++)
        acc[mt][nt] = __builtin_amdgcn_mfma_f32_16x16x32_bf16(a[nt], b[mt], acc[mt][nt], 0, 0, 0);
  }
#pragma unroll
  for (int mt = 0; mt < 2; mt++) {
    int m = bm * 32 + mt * 16 + col;
#pragma unroll
    for (int nt = 0; nt < 4; nt++) {
      int n = nbase + nt * 16 + quad * 4;
      f4 o = (acc[mt][nt] + *(const f4*)(b_comb + n)) * LOG2E;
      h2_t p0, p1;
      p0.x = (_Float16)o.x; p0.y = (_Float16)o.y;
      p1.x = (_Float16)o.z; p1.y = (_Float16)o.w;
      uint2 st; st.x = h2u(p0); st.y = h2u(p1);
      *(uint2*)(g_in + (long)m * G4 + n) = st;
    }
  }
}

// ---- kernel B v14: v13 + GATE-MAJOR MFMA/VALU interleave (1 wave/SIMD) --------------------
// R11 accounting: step = 1340 cy = 500 MFMA + 595 VALU + 245 idle — the VALU chain sits
// entirely AFTER the 32-MFMA cluster. At 1 wave/SIMD there is no partner wave to fill the
// MFMA issue-stall gaps (unlike v7's 2-wave regime where gate-major failed), so moving
// independent VALU BETWEEN MFMAs in program order converts sum -> max: 8 MFMAs for gate tau,
// then gate tau's extraction+sigmoid interleaved into gate tau+1's MFMA issue window.
// g-prefetch slots between gates 0 and 1. Target step ~1000-1150 cy.
__global__ __launch_bounds__(256, 1) void kernelB(const _Float16* __restrict__ g_in,
                                                  const unsigned char* __restrict__ W4,
                                                  _Float16* __restrict__ houts) {
  int bb = blockIdx.x;                           // batch
  int tid = threadIdx.x;
  int lane = tid & 63, w = tid >> 6;             // 4 waves, 1/SIMD
  int col = lane & 15, quad = lane >> 4;

  __shared__ __align__(16) unsigned char h4[2][144];   // [buf][unit>>1], 256 units nibble-packed

  for (int i = tid; i < 2 * 144; i += 256) ((unsigned char*)h4)[i] = 0;

  // W frags (B operand): wf4[(tau*4+s)*2+c] = W4 row (256*tau + 64*w + 16*s + col),
  // bytes [64c + 16*quad, +16) = k-slice [128c + 32*quad, +32).
  v4i wf4[32];
#pragma unroll
  for (int idx = 0; idx < 32; idx++) {
    int tau = idx >> 3, sp = (idx >> 1) & 3, c = idx & 1;
    const unsigned char* rp = W4 + (unsigned)(256 * tau + 64 * w + 16 * sp + col) * 128 + 64 * c + 16 * quad;
    wf4[idx] = *(const v4i*)rp;
  }

  f4 zero4 = {0.f, 0.f, 0.f, 0.f};
  asm volatile("" : "+v"(zero4));               // shared C=0 operand (4 regs, harmless)

  int myk = 64 * w + lane;                      // this lane's hidden unit (lane-contiguous)
  const unsigned char* ap0 = &h4[0][16 * quad]; // A-frag (h): k-slice by quad only
  const unsigned char* ap1 = &h4[1][16 * quad];
  const _Float16* gbase = g_in + (long)bb * G4 + myk;
  _Float16* hp = houts + (long)bb * H_ + myk;   // direct coalesced houts store pointer

  float cst = 0.f;
  float gi_ = (float)gbase[0];
  float gf_ = (float)gbase[256];
  float gg_ = (float)gbase[512];
  float go_ = (float)gbase[768];
  const _Float16* gp = gbase + (long)B_ * G4;   // running prefetch pointer (t=1)

  bool qb0 = (quad & 1) != 0;
  bool qb1 = (quad & 2) != 0;

  __syncthreads();

#pragma unroll 2
  for (int t = 0; t < T_; t++) {
    // A-frags (h) first: critical path out of the barrier
    const unsigned char* aptr = (t & 1) ? ap1 : ap0;
    v8i a0 = ext8(*(const v4i*)(aptr));         // chunk 0: k in [32q, +32)
    v8i a1 = ext8(*(const v4i*)(aptr + 64));    // chunk 1: k in [128+32q, +32)

    // ---- gate 0 (input): 8 MFMAs, then its extraction+sigmoid ----
    f4 c0[4];
#pragma unroll
    for (int s = 0; s < 4; s++)
      c0[s] = __builtin_amdgcn_mfma_scale_f32_16x16x128_f8f6f4(a0, ext8(wf4[s * 2 + 0]), zero4, 4, 4, 0, SC1, 0, SC1);
#pragma unroll
    for (int s = 0; s < 4; s++)
      c0[s] = __builtin_amdgcn_mfma_scale_f32_16x16x128_f8f6f4(a1, ext8(wf4[s * 2 + 1]), c0[s], 4, 4, 0, SC1, 0, SC1);
    float t0a = qb0 ? c0[1][0] : c0[0][0];
    float t0b = qb0 ? c0[3][0] : c0[2][0];
    float gi = (qb1 ? t0b : t0a) * DESCALE4 + gi_;
    float si = rcpf(1.f + exp2f_(-gi));

    // independent shadow work: next-g loads (hide under gate-1 MFMAs)
    _Float16 nh0 = gp[0];
    _Float16 nh1 = gp[256];
    _Float16 nh2 = gp[512];
    _Float16 nh3 = gp[768];
    gp += (long)B_ * G4;

    // ---- gate 1 (forget) ----
    f4 c1[4];
#pragma unroll
    for (int s = 0; s < 4; s++)
      c1[s] = __builtin_amdgcn_mfma_scale_f32_16x16x128_f8f6f4(a0, ext8(wf4[8 + s * 2 + 0]), zero4, 4, 4, 0, SC1, 0, SC1);
#pragma unroll
    for (int s = 0; s < 4; s++)
      c1[s] = __builtin_amdgcn_mfma_scale_f32_16x16x128_f8f6f4(a1, ext8(wf4[8 + s * 2 + 1]), c1[s], 4, 4, 0, SC1, 0, SC1);
    float t1a = qb0 ? c1[1][0] : c1[0][0];
    float t1b = qb0 ? c1[3][0] : c1[2][0];
    float gf = (qb1 ? t1b : t1a) * DESCALE4 + gf_;
    float sf = rcpf(1.f + exp2f_(-gf));

    // ---- gate 2 (cell candidate) ----
    f4 c2[4];
#pragma unroll
    for (int s = 0; s < 4; s++)
      c2[s] = __builtin_amdgcn_mfma_scale_f32_16x16x128_f8f6f4(a0, ext8(wf4[16 + s * 2 + 0]), zero4, 4, 4, 0, SC1, 0, SC1);
#pragma unroll
    for (int s = 0; s < 4; s++)
      c2[s] = __builtin_amdgcn_mfma_scale_f32_16x16x128_f8f6f4(a1, ext8(wf4[16 + s * 2 + 1]), c2[s], 4, 4, 0, SC1, 0, SC1);
    float t2a = qb0 ? c2[1][0] : c2[0][0];
    float t2b = qb0 ? c2[3][0] : c2[2][0];
    float gg = (qb1 ? t2b : t2a) * DESCALE4 + gg_;
    float tg = 1.f - 2.f * rcpf(1.f + exp2f_(gg + gg));            // tanh(gg_real)
    cst = sf * cst + si * tg;
    float tc_ = 1.f - 2.f * rcpf(1.f + exp2f_(2.88539008f * cst)); // tanh(cst)

    // ---- gate 3 (output): only this chain remains in the post-MFMA tail ----
    f4 c3[4];
#pragma unroll
    for (int s = 0; s < 4; s++)
      c3[s] = __builtin_amdgcn_mfma_scale_f32_16x16x128_f8f6f4(a0, ext8(wf4[24 + s * 2 + 0]), zero4, 4, 4, 0, SC1, 0, SC1);
#pragma unroll
    for (int s = 0; s < 4; s++)
      c3[s] = __builtin_amdgcn_mfma_scale_f32_16x16x128_f8f6f4(a1, ext8(wf4[24 + s * 2 + 1]), c3[s], 4, 4, 0, SC1, 0, SC1);
    float t3a = qb0 ? c3[1][0] : c3[0][0];
    float t3b = qb0 ? c3[3][0] : c3[2][0];
    float go = (qb1 ? t3b : t3a) * DESCALE4 + go_;
    float so = rcpf(1.f + exp2f_(-go));
    float h = so * tc_;

    // h -> fp4 nibble; neighbor unit myk^1 = lane^1; even lanes write the byte
    unsigned code = f32_e2m1(h * HSCALE4);
    unsigned pc = (unsigned)__shfl_xor((int)code, 1);
    if (!(lane & 1)) h4[1 - (t & 1)][32 * w + (lane >> 1)] = (unsigned char)(code | (pc << 4));

    // direct coalesced houts store (64 contiguous f16 per wave; never drained in-loop)
    *hp = (_Float16)h;
    hp += (long)B_ * H_;

    // consume prefetch
    gi_ = (float)nh0; gf_ = (float)nh1; gg_ = (float)nh2; go_ = (float)nh3;
    block_sync_lds();
  }
}

// ---- kernel C: emissions = houts(f16) @ W_lin^T + b_lin -----------------------------------
__global__ __launch_bounds__(256) void kernelC(const _Float16* __restrict__ houts,
                                               const float* __restrict__ W_lin,
                                               const float* __restrict__ b_lin,
                                               float* __restrict__ em) {
  __shared__ float hs[32][260];
  __shared__ float wl[20][260];
  __shared__ float bl[20];
  int bm = blockIdx.x;
  int tid = threadIdx.x;
  for (int i = tid; i < 32 * 64; i += 256) {
    int r = i >> 6, c = i & 63;
    uint2 v = *(const uint2*)(houts + ((long)(bm * 32 + r)) * H_ + c * 4);
    h2_t h0 = u2h(v.x), h1 = u2h(v.y);
    *(float4*)&hs[r][c * 4] = make_float4((float)h0.x, (float)h0.y, (float)h1.x, (float)h1.y);
  }
  for (int i = tid; i < 20 * 64; i += 256) {
    int k = i >> 6, c = i & 63;
    *(float4*)&wl[k][c * 4] = *(const float4*)(W_lin + k * H_ + c * 4);
  }
  if (tid < 20) bl[tid] = b_lin[tid];
  __syncthreads();
  for (int o = tid; o < 32 * 20; o += 256) {
    int r = o / 20, k = o % 20;
    float s = 0.f;
#pragma unroll 4
    for (int i = 0; i < H_; i++) s += hs[r][i] * wl[k][i];
    em[(long)bm * 32 * K_ + o] = s + bl[k];
  }
}

// ---- kernel D: CRF. wave0: rel-log2-domain forward DP (tree-reduced dot); wave1: gold. ----
__global__ __launch_bounds__(128) void kernelD(const float* __restrict__ em,
                                               const int* __restrict__ labels,
                                               const float* __restrict__ start_t,
                                               const float* __restrict__ end_t,
                                               const float* __restrict__ trans,
                                               float* __restrict__ out) {
  int b = blockIdx.x;
  int tid = threadIdx.x;
  int lane = tid & 63;
  int wv = tid >> 6;
  if (wv == 0) {
    int k = lane & 31;
    bool vk = (k < K_);
    int kk = vk ? k : 0;
    float E[20];   // linear-domain exp(trans[j][k])
#pragma unroll
    for (int j = 0; j < 20; j++) E[j] = vk ? __expf(trans[j * 20 + k]) : 0.f;
    float end2 = vk ? end_t[kk] * LOG2E : -1e30f;
    float raw0 = (start_t[kk] + em[b * K_ + kk]) * LOG2E;
    float D2 = __shfl(raw0, 0, 32);
    float a2 = vk ? (raw0 - D2) : -1e30f;
    float C2 = D2;
    float emk = em[(64 + b) * K_ + kk];   // t = 1
    for (int t = 1; t < T_; t++) {
      float em_next = (t < T_ - 1) ? em[((long)(t + 1) * B_ + b) * K_ + kk] : 0.f;
      float e = exp2f_(a2);              // invalid lanes: exp2(-1e30) = 0
      // tree-reduced 20-term dot: 4 partials of depth 5 instead of one depth-20 fma chain
      float S0 = 0.f, S1 = 0.f, S2 = 0.f, S3 = 0.f;
#pragma unroll
      for (int j = 0; j < 5; j++) {
        S0 = fmaf(__shfl(e, j, 32),      E[j],      S0);
        S1 = fmaf(__shfl(e, j + 5, 32),  E[j + 5],  S1);
        S2 = fmaf(__shfl(e, j + 10, 32), E[j + 10], S2);
        S3 = fmaf(__shfl(e, j + 15, 32), E[j + 15], S3);
      }
      float S = (S0 + S1) + (S2 + S3);
      float raw = emk * LOG2E + __log2f(S);
      float Dn = __shfl(raw, 0, 32);
      a2 = vk ? (raw - Dn) : -1e30f;
      C2 += Dn;
      emk = em_next;
    }
    float fin = vk ? (a2 + end2) : -1e30f;
    float m = fin;
#pragma unroll
    for (int off = 16; off >= 1; off >>= 1) m = fmaxf(m, __shfl_xor(m, off, 32));
    float e = vk ? exp2f_(fin - m) : 0.f;
#pragma unroll
    for (int off = 16; off >= 1; off >>= 1) e += __shfl_xor(e, off, 32);
    if (lane == 0) atomicAdd(out, LN2 * (C2 + m + __log2f(e)));
  } else {
    // gold-path score: order-free sum, lane l covers t = 8l..8l+7
    int t0 = 8 * lane;
    int tags[9];
#pragma unroll
    for (int i = 0; i < 9; i++) {
      int t = t0 - 1 + i;
      tags[i] = (t >= 0) ? labels[t * B_ + b] : 0;
    }
    float sc = 0.f;
#pragma unroll
    for (int i = 1; i < 9; i++) {
      int t = t0 - 1 + i;
      float v = em[((long)t * B_ + b) * K_ + tags[i]];
      v += (t > 0) ? trans[tags[i - 1] * 20 + tags[i]] : start_t[tags[i]];
      sc += v;
    }
#pragma unroll
    for (int off = 32; off >= 1; off >>= 1) sc += __shfl_xor(sc, off, 64);
    if (lane == 0) {
      sc += end_t[labels[511 * B_ + b]];
      atomicAdd(out, -sc);
    }
  }
}

extern "C" void kernel_launch(void* const* d_in, const int* in_sizes, int n_in,
                              void* d_out, int out_size, void* d_ws, size_t ws_size,
                              hipStream_t stream) {
  const int*   inp     = (const int*)d_in[0];
  const int*   labels  = (const int*)d_in[1];
  const float* emb     = (const float*)d_in[2];
  const float* w_ih    = (const float*)d_in[3];
  const float* w_hh    = (const float*)d_in[4];
  const float* b_ih    = (const float*)d_in[5];
  const float* b_hh    = (const float*)d_in[6];
  const float* W_lin   = (const float*)d_in[7];
  const float* b_lin   = (const float*)d_in[8];
  const float* start_t = (const float*)d_in[9];
  const float* end_t   = (const float*)d_in[10];
  const float* trans   = (const float*)d_in[11];
  float* out = (float*)d_out;
  char* ws = (char*)d_ws;
  (void)ws_size;

  // ws layout (bytes), total ~91.6 MB:
  _Float16*       g_in   = (_Float16*)(ws);                       // 67,108,864 (T*B*1024 f16)
  unsigned short* Xh     = (unsigned short*)(ws + 67108864);      // 20,971,520 (32768x320 bf16)
  _Float16*       houts  = (_Float16*)(ws + 67108864);            // 16,777,216 — ALIASES Xh (Xh dead after kernelA)
  float*          em     = (float*)(ws + 88080384);               //  2,621,440 (T*B*K f32)
  unsigned short* wA     = (unsigned short*)(ws + 90701824);      //    655,360 (10x4x1024x8 bf16)
  unsigned char*  W4     = (unsigned char*)(ws + 91357184);       //    131,072 (1024x128 fp4 nibbles)
  float*          b_comb = (float*)(ws + 91619328);               //      4,096

  prep_kernel<<<2048, 256, 0, stream>>>(inp, emb, w_ih, w_hh, b_ih, b_hh, Xh, wA, W4, b_comb, out);
  kernelA<<<4096, 256, 0, stream>>>(Xh, wA, b_comb, g_in);
  kernelB<<<64, 256, 0, stream>>>(g_in, W4, houts);
  kernelC<<<1024, 256, 0, stream>>>(houts, W_lin, b_lin, em);
  kernelD<<<64, 128, 0, stream>>>(em, labels, start_t, end_t, trans, out);
}

// Round 13
// 572.663 us; speedup vs baseline: 1.0480x; 1.0480x over previous
//
#include <hip/hip_runtime.h>
#include <math.h>

#define T_ 512
#define B_ 64
#define V_ 50000
#define E_ 300
#define H_ 256
#define K_ 20
#define G4 1024  /* 4*H */
#define LOG2E 1.44269504f
#define LN2 0.69314718f

typedef float f4 __attribute__((ext_vector_type(4)));
typedef int v4i __attribute__((ext_vector_type(4)));
typedef int v8i __attribute__((ext_vector_type(8)));
typedef short bf16x8 __attribute__((ext_vector_type(8)));
typedef _Float16 h2_t __attribute__((ext_vector_type(2)));
union U32H2 { unsigned u; h2_t h; };
__device__ __forceinline__ h2_t u2h(unsigned u) { U32H2 x; x.u = u; return x.h; }
__device__ __forceinline__ unsigned h2u(h2_t h) { U32H2 x; x.h = h; return x.u; }

__device__ __forceinline__ float rcpf(float x) { return __builtin_amdgcn_rcpf(x); }
__device__ __forceinline__ float exp2f_(float x) { return __builtin_amdgcn_exp2f(x); }

__device__ __forceinline__ unsigned short f32_bf16(float x) {
  union { float f; unsigned u; } v; v.f = x;
  v.u += 0x7FFFu + ((v.u >> 16) & 1u);   // RTNE
  return (unsigned short)(v.u >> 16);
}

// e2m1 (fp4) quantizer: values {0,.5,1,1.5,2,3,4,6}, RTNE thresholds at midpoints.
__device__ __forceinline__ unsigned f32_e2m1(float x) {
  float a = fabsf(x);
  unsigned m = (a >= 0.25f) + (a >= 0.75f) + (a >= 1.25f) + (a >= 1.75f)
             + (a >= 2.5f)  + (a >= 3.5f)  + (a >= 5.f);
  return (x < 0.f ? 8u : 0u) | m;
}

// undef-extend a v4i to the v8i operand slot (fp4 fmt reads only v[0:3])
__device__ __forceinline__ v8i ext8(v4i x) {
  return __builtin_shufflevector(x, x, 0, 1, 2, 3, -1, -1, -1, -1);
}

// LDS-only barrier (R2: neutral vs __syncthreads; keeps vmcnt in flight).
__device__ __forceinline__ void block_sync_lds() {
  asm volatile("s_waitcnt lgkmcnt(0)" ::: "memory");
  __builtin_amdgcn_s_barrier();
}

#define WSCALE4 64.f     /* fp4 e2m1 weight scale: w*64 in [-4,4] */
#define HSCALE4 4.f      /* fp4 e2m1 h scale: h*4 in [-4,4] */
#define DESCALE4 (LOG2E / (WSCALE4 * HSCALE4))
#define SC1 0x7F7F7F7F   /* e8m0 exponent 127 = scale 1.0 (all 4 MX blocks) */

// ---- prep (small now): pack w_ih A-frags, quantize w_hh fp4, combine biases, zero out ----
// (X-gather fused into kernelA; Xh buffer deleted.)
__global__ void prep_kernel(const float* __restrict__ w_ih, const float* __restrict__ w_hh,
                            const float* __restrict__ b_ih, const float* __restrict__ b_hh,
                            unsigned short* __restrict__ wA,
                            unsigned char* __restrict__ W4,
                            float* __restrict__ b_comb, float* __restrict__ out) {
  int tid = blockIdx.x * blockDim.x + threadIdx.x;
  int nth = gridDim.x * blockDim.x;
  for (int i = tid; i < 10 * 4 * 1024 * 8; i += nth) {
    int j = i & 7, n = (i >> 3) & 1023, q = (i >> 13) & 3, c = i >> 15;
    int k = c * 32 + q * 8 + j;
    wA[i] = (k < E_) ? f32_bf16(w_ih[n * E_ + k]) : 0;
  }
  // W4[row][kb] = e2m1(w[row][2kb]*64) | e2m1(w[row][2kb+1]*64)<<4  (nibble k-pairs)
  for (int i = tid; i < G4 * (H_ / 2); i += nth) {
    int row = i >> 7, kb = i & 127;
    unsigned lo = f32_e2m1(w_hh[row * H_ + 2 * kb]     * WSCALE4);
    unsigned hi = f32_e2m1(w_hh[row * H_ + 2 * kb + 1] * WSCALE4);
    W4[i] = (unsigned char)(lo | (hi << 4));
  }
  for (int i = tid; i < G4; i += nth) b_comb[i] = b_ih[i] + b_hh[i];
  if (tid == 0) out[0] = 0.f;
}

// ---- kernel A (fused gather + internal bn loop): g_in = (emb[inp] @ w_ih^T + b)*log2e ----
// 1024 blocks (was 4096): each block gathers its 32-row X tile from emb ONCE (prep's Xh
// round-trip — 21MB write + 21MB read — deleted), then loops bn over all 4 output quarters
// reusing the LDS tile. wA stays global (640KB, L2-resident).
__global__ __launch_bounds__(256) void kernelA(const int* __restrict__ inp,
                                               const float* __restrict__ emb,
                                               const unsigned short* __restrict__ wA,
                                               const float* __restrict__ b_comb,
                                               _Float16* __restrict__ g_in) {
  __shared__ __align__(16) unsigned short xs[32 * 328];
  int bm = blockIdx.x;
  int tid = threadIdx.x;
  for (int i = tid; i < 32 * 80; i += 256) {
    int row = i / 80, c4 = i % 80, k = c4 * 4;
    ushort4 st;
    if (c4 < 75) {
      int tok = inp[bm * 32 + row];
      float4 v = *(const float4*)(emb + (long)tok * E_ + k);
      st.x = f32_bf16(v.x); st.y = f32_bf16(v.y); st.z = f32_bf16(v.z); st.w = f32_bf16(v.w);
    } else {
      st.x = st.y = st.z = st.w = 0;   // pad K 300 -> 320
    }
    *(ushort4*)&xs[row * 328 + k] = st;
  }
  __syncthreads();
  int lane = tid & 63, w = tid >> 6, col = lane & 15, quad = lane >> 4;
  for (int bn = 0; bn < 4; bn++) {
    int nbase = bn * 256 + w * 64;
    f4 acc[2][4];
#pragma unroll
    for (int mt = 0; mt < 2; mt++)
#pragma unroll
      for (int nt = 0; nt < 4; nt++) acc[mt][nt] = (f4){0.f, 0.f, 0.f, 0.f};
#pragma unroll 2
    for (int c = 0; c < 10; c++) {
      bf16x8 a[4], b[2];
#pragma unroll
      for (int nt = 0; nt < 4; nt++)
        a[nt] = *(const bf16x8*)(wA + (((long)c * 4 + quad) * 1024 + nbase + nt * 16 + col) * 8);
#pragma unroll
      for (int mt = 0; mt < 2; mt++)
        b[mt] = *(const bf16x8*)&xs[(mt * 16 + col) * 328 + c * 32 + quad * 8];
#pragma unroll
      for (int mt = 0; mt < 2; mt++)
#pragma unroll
        for (int nt = 0; nt < 4; nt++)
          acc[mt][nt] = __builtin_amdgcn_mfma_f32_16x16x32_bf16(a[nt], b[mt], acc[mt][nt], 0, 0, 0);
    }
#pragma unroll
    for (int mt = 0; mt < 2; mt++) {
      int m = bm * 32 + mt * 16 + col;
#pragma unroll
      for (int nt = 0; nt < 4; nt++) {
        int n = nbase + nt * 16 + quad * 4;
        f4 o = (acc[mt][nt] + *(const f4*)(b_comb + n)) * LOG2E;
        h2_t p0, p1;
        p0.x = (_Float16)o.x; p0.y = (_Float16)o.y;
        p1.x = (_Float16)o.z; p1.y = (_Float16)o.w;
        uint2 st; st.x = h2u(p0); st.y = h2u(p1);
        *(uint2*)(g_in + (long)m * G4 + n) = st;
      }
    }
  }
}

// ---- kernel B v13 (exact revert — best measured: 286.8 us) --------------------------------
// D = h(A) x W(B) swap: D col = W-unit, rows = batch replicas (all f4 comps identical).
// unit myk = 64w + lane -> gate tau = acc[4tau+quad][0]; coalesced houts/g_in access.
// R12 lesson (v7+v14): within a wave, issue ALL independent MFMAs first, THEN dependent
// VALU — interleaving dependent extracts between MFMA clusters stalls in-order issue.
__global__ __launch_bounds__(256, 1) void kernelB(const _Float16* __restrict__ g_in,
                                                  const unsigned char* __restrict__ W4,
                                                  _Float16* __restrict__ houts) {
  int bb = blockIdx.x;                           // batch
  int tid = threadIdx.x;
  int lane = tid & 63, w = tid >> 6;             // 4 waves, 1/SIMD
  int col = lane & 15, quad = lane >> 4;

  __shared__ __align__(16) unsigned char h4[2][144];   // [buf][unit>>1], 256 units nibble-packed

  for (int i = tid; i < 2 * 144; i += 256) ((unsigned char*)h4)[i] = 0;

  // W frags (B operand): wf4[(tau*4+s)*2+c] = W4 row (256*tau + 64*w + 16*s + col),
  // bytes [64c + 16*quad, +16) = k-slice [128c + 32*quad, +32).
  v4i wf4[32];
#pragma unroll
  for (int idx = 0; idx < 32; idx++) {
    int tau = idx >> 3, sp = (idx >> 1) & 3, c = idx & 1;
    const unsigned char* rp = W4 + (unsigned)(256 * tau + 64 * w + 16 * sp + col) * 128 + 64 * c + 16 * quad;
    wf4[idx] = *(const v4i*)rp;
  }

  f4 zero4 = {0.f, 0.f, 0.f, 0.f};
  asm volatile("" : "+v"(zero4));               // shared C=0 operand (4 regs, harmless)

  int myk = 64 * w + lane;                      // this lane's hidden unit (lane-contiguous)
  const unsigned char* ap0 = &h4[0][16 * quad]; // A-frag (h): k-slice by quad only
  const unsigned char* ap1 = &h4[1][16 * quad];
  const _Float16* gbase = g_in + (long)bb * G4 + myk;
  _Float16* hp = houts + (long)bb * H_ + myk;   // direct coalesced houts store pointer

  float cst = 0.f;
  float gi_ = (float)gbase[0];
  float gf_ = (float)gbase[256];
  float gg_ = (float)gbase[512];
  float go_ = (float)gbase[768];
  const _Float16* gp = gbase + (long)B_ * G4;   // running prefetch pointer (t=1)

  bool qb0 = (quad & 1) != 0;
  bool qb1 = (quad & 2) != 0;

  __syncthreads();

#pragma unroll 2
  for (int t = 0; t < T_; t++) {
    // 1. A-frags (h) first: the critical path out of the barrier
    const unsigned char* aptr = (t & 1) ? ap1 : ap0;
    v8i a0 = ext8(*(const v4i*)(aptr));         // chunk 0: k in [32q, +32)
    v8i a1 = ext8(*(const v4i*)(aptr + 64));    // chunk 1: k in [128+32q, +32)

    // 2. MFMAs: acc[tau*4+s] over 2 K-chunks; A = h (fp4), B = W (fp4)
    f4 acc[16];
#pragma unroll
    for (int i = 0; i < 16; i++)
      acc[i] = __builtin_amdgcn_mfma_scale_f32_16x16x128_f8f6f4(a0, ext8(wf4[i * 2 + 0]), zero4, 4, 4, 0, SC1, 0, SC1);
#pragma unroll
    for (int i = 0; i < 16; i++)
      acc[i] = __builtin_amdgcn_mfma_scale_f32_16x16x128_f8f6f4(a1, ext8(wf4[i * 2 + 1]), acc[i], 4, 4, 0, SC1, 0, SC1);

    // 3. shadow: issue next-g loads (raw f16, cvt at consume)
    _Float16 nh0 = gp[0];
    _Float16 nh1 = gp[256];
    _Float16 nh2 = gp[512];
    _Float16 nh3 = gp[768];
    gp += (long)B_ * G4;

    // 4. extraction: gate tau = acc[4*tau + quad][0]  (12 cndmask total)
    float t0a = qb0 ? acc[1][0]  : acc[0][0];
    float t0b = qb0 ? acc[3][0]  : acc[2][0];
    float gir = qb1 ? t0b : t0a;
    float t1a = qb0 ? acc[5][0]  : acc[4][0];
    float t1b = qb0 ? acc[7][0]  : acc[6][0];
    float gfr = qb1 ? t1b : t1a;
    float t2a = qb0 ? acc[9][0]  : acc[8][0];
    float t2b = qb0 ? acc[11][0] : acc[10][0];
    float ggr = qb1 ? t2b : t2a;
    float t3a = qb0 ? acc[13][0] : acc[12][0];
    float t3b = qb0 ? acc[15][0] : acc[14][0];
    float gor = qb1 ? t3b : t3a;

    float gi = gir * DESCALE4 + gi_;
    float gf = gfr * DESCALE4 + gf_;
    float gg = ggr * DESCALE4 + gg_;
    float go = gor * DESCALE4 + go_;
    float si = rcpf(1.f + exp2f_(-gi));
    float sf = rcpf(1.f + exp2f_(-gf));
    float so = rcpf(1.f + exp2f_(-go));
    float tg = 1.f - 2.f * rcpf(1.f + exp2f_(gg + gg));            // tanh(gg_real)
    cst = sf * cst + si * tg;
    float tc_ = 1.f - 2.f * rcpf(1.f + exp2f_(2.88539008f * cst)); // tanh(cst)
    float h = so * tc_;

    // 5. h -> fp4 nibble; neighbor unit myk^1 = lane^1; even lanes write the byte
    unsigned code = f32_e2m1(h * HSCALE4);
    unsigned pc = (unsigned)__shfl_xor((int)code, 1);
    if (!(lane & 1)) h4[1 - (t & 1)][32 * w + (lane >> 1)] = (unsigned char)(code | (pc << 4));

    // 6. direct coalesced houts store (64 contiguous f16 per wave; never drained in-loop)
    *hp = (_Float16)h;
    hp += (long)B_ * H_;

    // 7. consume prefetch
    gi_ = (float)nh0; gf_ = (float)nh1; gg_ = (float)nh2; go_ = (float)nh3;
    block_sync_lds();
  }
}

// ---- kernel C: emissions = houts(f16) @ W_lin^T + b_lin -----------------------------------
__global__ __launch_bounds__(256) void kernelC(const _Float16* __restrict__ houts,
                                               const float* __restrict__ W_lin,
                                               const float* __restrict__ b_lin,
                                               float* __restrict__ em) {
  __shared__ float hs[32][260];
  __shared__ float wl[20][260];
  __shared__ float bl[20];
  int bm = blockIdx.x;
  int tid = threadIdx.x;
  for (int i = tid; i < 32 * 64; i += 256) {
    int r = i >> 6, c = i & 63;
    uint2 v = *(const uint2*)(houts + ((long)(bm * 32 + r)) * H_ + c * 4);
    h2_t h0 = u2h(v.x), h1 = u2h(v.y);
    *(float4*)&hs[r][c * 4] = make_float4((float)h0.x, (float)h0.y, (float)h1.x, (float)h1.y);
  }
  for (int i = tid; i < 20 * 64; i += 256) {
    int k = i >> 6, c = i & 63;
    *(float4*)&wl[k][c * 4] = *(const float4*)(W_lin + k * H_ + c * 4);
  }
  if (tid < 20) bl[tid] = b_lin[tid];
  __syncthreads();
  for (int o = tid; o < 32 * 20; o += 256) {
    int r = o / 20, k = o % 20;
    float s = 0.f;
#pragma unroll 4
    for (int i = 0; i < H_; i++) s += hs[r][i] * wl[k][i];
    em[(long)bm * 32 * K_ + o] = s + bl[k];
  }
}

// ---- kernel D: CRF. wave0: rel-log2-domain forward DP (tree-reduced dot); wave1: gold. ----
__global__ __launch_bounds__(128) void kernelD(const float* __restrict__ em,
                                               const int* __restrict__ labels,
                                               const float* __restrict__ start_t,
                                               const float* __restrict__ end_t,
                                               const float* __restrict__ trans,
                                               float* __restrict__ out) {
  int b = blockIdx.x;
  int tid = threadIdx.x;
  int lane = tid & 63;
  int wv = tid >> 6;
  if (wv == 0) {
    int k = lane & 31;
    bool vk = (k < K_);
    int kk = vk ? k : 0;
    float E[20];   // linear-domain exp(trans[j][k])
#pragma unroll
    for (int j = 0; j < 20; j++) E[j] = vk ? __expf(trans[j * 20 + k]) : 0.f;
    float end2 = vk ? end_t[kk] * LOG2E : -1e30f;
    float raw0 = (start_t[kk] + em[b * K_ + kk]) * LOG2E;
    float D2 = __shfl(raw0, 0, 32);
    float a2 = vk ? (raw0 - D2) : -1e30f;
    float C2 = D2;
    float emk = em[(64 + b) * K_ + kk];   // t = 1
    for (int t = 1; t < T_; t++) {
      float em_next = (t < T_ - 1) ? em[((long)(t + 1) * B_ + b) * K_ + kk] : 0.f;
      float e = exp2f_(a2);              // invalid lanes: exp2(-1e30) = 0
      // tree-reduced 20-term dot: 4 partials of depth 5 instead of one depth-20 fma chain
      float S0 = 0.f, S1 = 0.f, S2 = 0.f, S3 = 0.f;
#pragma unroll
      for (int j = 0; j < 5; j++) {
        S0 = fmaf(__shfl(e, j, 32),      E[j],      S0);
        S1 = fmaf(__shfl(e, j + 5, 32),  E[j + 5],  S1);
        S2 = fmaf(__shfl(e, j + 10, 32), E[j + 10], S2);
        S3 = fmaf(__shfl(e, j + 15, 32), E[j + 15], S3);
      }
      float S = (S0 + S1) + (S2 + S3);
      float raw = emk * LOG2E + __log2f(S);
      float Dn = __shfl(raw, 0, 32);
      a2 = vk ? (raw - Dn) : -1e30f;
      C2 += Dn;
      emk = em_next;
    }
    float fin = vk ? (a2 + end2) : -1e30f;
    float m = fin;
#pragma unroll
    for (int off = 16; off >= 1; off >>= 1) m = fmaxf(m, __shfl_xor(m, off, 32));
    float e = vk ? exp2f_(fin - m) : 0.f;
#pragma unroll
    for (int off = 16; off >= 1; off >>= 1) e += __shfl_xor(e, off, 32);
    if (lane == 0) atomicAdd(out, LN2 * (C2 + m + __log2f(e)));
  } else {
    // gold-path score: order-free sum, lane l covers t = 8l..8l+7
    int t0 = 8 * lane;
    int tags[9];
#pragma unroll
    for (int i = 0; i < 9; i++) {
      int t = t0 - 1 + i;
      tags[i] = (t >= 0) ? labels[t * B_ + b] : 0;
    }
    float sc = 0.f;
#pragma unroll
    for (int i = 1; i < 9; i++) {
      int t = t0 - 1 + i;
      float v = em[((long)t * B_ + b) * K_ + tags[i]];
      v += (t > 0) ? trans[tags[i - 1] * 20 + tags[i]] : start_t[tags[i]];
      sc += v;
    }
#pragma unroll
    for (int off = 32; off >= 1; off >>= 1) sc += __shfl_xor(sc, off, 64);
    if (lane == 0) {
      sc += end_t[labels[511 * B_ + b]];
      atomicAdd(out, -sc);
    }
  }
}

extern "C" void kernel_launch(void* const* d_in, const int* in_sizes, int n_in,
                              void* d_out, int out_size, void* d_ws, size_t ws_size,
                              hipStream_t stream) {
  const int*   inp     = (const int*)d_in[0];
  const int*   labels  = (const int*)d_in[1];
  const float* emb     = (const float*)d_in[2];
  const float* w_ih    = (const float*)d_in[3];
  const float* w_hh    = (const float*)d_in[4];
  const float* b_ih    = (const float*)d_in[5];
  const float* b_hh    = (const float*)d_in[6];
  const float* W_lin   = (const float*)d_in[7];
  const float* b_lin   = (const float*)d_in[8];
  const float* start_t = (const float*)d_in[9];
  const float* end_t   = (const float*)d_in[10];
  const float* trans   = (const float*)d_in[11];
  float* out = (float*)d_out;
  char* ws = (char*)d_ws;
  (void)ws_size;

  // ws layout (bytes), total ~91.6 MB (Xh slot now used only by houts):
  _Float16*       g_in   = (_Float16*)(ws);                       // 67,108,864 (T*B*1024 f16)
  _Float16*       houts  = (_Float16*)(ws + 67108864);            // 16,777,216
  float*          em     = (float*)(ws + 88080384);               //  2,621,440 (T*B*K f32)
  unsigned short* wA     = (unsigned short*)(ws + 90701824);      //    655,360 (10x4x1024x8 bf16)
  unsigned char*  W4     = (unsigned char*)(ws + 91357184);       //    131,072 (1024x128 fp4 nibbles)
  float*          b_comb = (float*)(ws + 91619328);               //      4,096

  prep_kernel<<<1024, 256, 0, stream>>>(w_ih, w_hh, b_ih, b_hh, wA, W4, b_comb, out);
  kernelA<<<1024, 256, 0, stream>>>(inp, emb, wA, b_comb, g_in);
  kernelB<<<64, 256, 0, stream>>>(g_in, W4, houts);
  kernelC<<<1024, 256, 0, stream>>>(houts, W_lin, b_lin, em);
  kernelD<<<64, 128, 0, stream>>>(em, labels, start_t, end_t, trans, out);
}